// Round 9
// baseline (92.555 us; speedup 1.0000x reference)
//
#include <hip/hip_runtime.h>

typedef unsigned short ushortT;
typedef short bf16x8 __attribute__((ext_vector_type(8)));
typedef float f32x4 __attribute__((ext_vector_type(4)));
#define MFMA __builtin_amdgcn_mfma_f32_16x16x32_bf16

#define B_   16
#define L_   512
#define N_   64
#define D_   256
#define Q_   128          // chunk length
#define C_   4            // chunks
#define KROWS 144         // Kpad rows: tau = row-16, rows 0..15 zero

// ---- workspace byte offsets (total ~17.1 MB) ------------------------------
#define OFF_UTH   0u                    // u_T hi  [64 bc][256 d][128 j] bf16
#define OFF_UTL   4194304u              // u_T lo
#define OFF_W4    8388608u              // W planes {reh,rel,imh,iml} [64 bc][256 d][64 n] bf16
#define W4PLANE   2097152u
#define OFF_KPAD  16777216u             // Kpad [144][256] f32
#define OFF_ABT   16924672u             // AbReh,AbRel,AbImh,AbIml each 64x128 bf16 (16384 B)
#define OFF_PT    16990208u             // P1h,P1l,P2h,P2l each 128x64 bf16 (16384 B)

__device__ __forceinline__ ushortT f2bf(float f) {
    unsigned u = __float_as_uint(f);
    return (ushortT)((u + 0x7FFFu + ((u >> 16) & 1u)) >> 16);   // RNE
}
__device__ __forceinline__ float bf2f(ushortT h) {
    return __uint_as_float(((unsigned)h) << 16);
}
__device__ __forceinline__ void split2(float f, ushortT& hi, ushortT& lo) {
    hi = f2bf(f); lo = f2bf(f - bf2f(hi));
}

// ---------------------------------------------------------------------------
// KT: blocks 0..143 -> Kpad rows; 144..207 -> u transpose+split; 208 -> tables
// ---------------------------------------------------------------------------
__global__ __launch_bounds__(256)
void kt_kernel(const float* __restrict__ u,
               const float* __restrict__ Lre, const float* __restrict__ Lim,
               const float* __restrict__ Bre, const float* __restrict__ Bim,
               const float* __restrict__ Pre, const float* __restrict__ Pim,
               const float* __restrict__ logdt, char* __restrict__ ws)
{
    const int blk = blockIdx.x, t = threadIdx.x;
    const float dt = expf(logdt[0]);

    if (blk < KROWS) {                       // ---- Kpad[row][d] (r3-verified)
        float* Kpad = (float*)(ws + OFF_KPAD);
        __shared__ float U[N_], V[N_];
        const int row = blk, tau = row - 16, d = t;
        if (tau < 0) { Kpad[row * D_ + d] = 0.f; return; }
        if (d < N_) {
            const float eL = expf(Lre[d]);
            const float wre = -eL * cosf(Lim[d]), wim = -eL * sinf(Lim[d]);
            const float er = expf(tau * dt * wre);
            float sn, cs; sincosf(tau * dt * wim, &sn, &cs);
            const float Ar = er * cs, Ai = er * sn;
            const float bdr = dt * Bre[d], bdi = dt * Bim[d];
            U[d] = bdr * Ar - bdi * Ai;
            V[d] = bdi * Ar + bdr * Ai;
        }
        __syncthreads();
        float acc = 0.f;
        #pragma unroll 8
        for (int n = 0; n < N_; ++n)
            acc = fmaf(Pre[n * D_ + d], U[n], fmaf(-Pim[n * D_ + d], V[n], acc));
        Kpad[row * D_ + d] = acc;

    } else if (blk < 208) {                  // ---- u_T transpose + hi/lo split
        const int bc = blk - 144, b = bc >> 2, c = bc & 3;
        ushortT* uth = (ushortT*)(ws + OFF_UTH) + (size_t)bc * 32768;
        ushortT* utl = (ushortT*)(ws + OFF_UTL) + (size_t)bc * 32768;
        const float* ub = u + ((size_t)(b * L_ + c * Q_)) * D_ + t;   // +j*D_
        for (int j0 = 0; j0 < Q_; j0 += 8) {
            union { ushortT us[8]; uint4 v; } ph, pl;
            #pragma unroll
            for (int jj = 0; jj < 8; ++jj) {
                const float v = ub[(j0 + jj) * D_];
                split2(v, ph.us[jj], pl.us[jj]);
            }
            *(uint4*)(uth + (size_t)t * Q_ + j0) = ph.v;
            *(uint4*)(utl + (size_t)t * Q_ + j0) = pl.v;
        }

    } else {                                 // ---- Abar & P power tables
        ushortT* AbReh = (ushortT*)(ws + OFF_ABT);
        ushortT* AbRel = AbReh + 8192;
        ushortT* AbImh = AbReh + 16384;
        ushortT* AbIml = AbReh + 24576;
        ushortT* P1h = (ushortT*)(ws + OFF_PT);
        ushortT* P1l = P1h + 8192;
        ushortT* P2h = P1h + 16384;
        ushortT* P2l = P1h + 24576;
        const int n = t & 63, q = t >> 6;
        const float eL = expf(Lre[n]);
        const float xr = dt * (-eL * cosf(Lim[n]));
        const float xi = dt * (-eL * sinf(Lim[n]));
        for (int j = q * 32; j < q * 32 + 32; ++j) {    // Abar[n][j]=a^(127-j)
            const float p = (float)(127 - j);
            const float er = expf(p * xr);
            float sn, cs; sincosf(p * xi, &sn, &cs);
            split2(er * cs, AbReh[n * Q_ + j], AbRel[n * Q_ + j]);
            split2(er * sn, AbImh[n * Q_ + j], AbIml[n * Q_ + j]);
        }
        for (int i = q * 32; i < q * 32 + 32; ++i) {    // P[i][n]: a^(i+1)
            const float p = (float)(i + 1);
            const float er = expf(p * xr);
            float sn, cs; sincosf(p * xi, &sn, &cs);
            split2(er * cs,  P1h[i * N_ + n], P1l[i * N_ + n]);
            split2(-er * sn, P2h[i * N_ + n], P2l[i * N_ + n]);  // -Im
        }
    }
}

// ---------------------------------------------------------------------------
// G1S: per (b, dq) block: serial over c: W=C*h store; g = Abar@u (MFMA,
// split bf16); h = a^128 h + Bd*g.  4 waves = 4 n-tiles. d-range = 32.
// ---------------------------------------------------------------------------
__global__ __launch_bounds__(256)
void g1s_kernel(const float* __restrict__ Lre, const float* __restrict__ Lim,
                const float* __restrict__ Bre, const float* __restrict__ Bim,
                const float* __restrict__ Pre, const float* __restrict__ Pim,
                const float* __restrict__ logdt, char* __restrict__ ws)
{
    __shared__ ushortT Wl[4][32][65];        // plane, d_loc, n (pad 65)

    const int blk = blockIdx.x, b = blk >> 3, dq = blk & 7;
    const int t = threadIdx.x, l = t & 63, w = t >> 6;     // w = n-tile
    const float dt = expf(logdt[0]);

    const ushortT* AbReh = (const ushortT*)(ws + OFF_ABT);
    const ushortT* AbRel = AbReh + 8192;
    const ushortT* AbImh = AbReh + 16384;
    const ushortT* AbIml = AbReh + 24576;
    const ushortT* uthB = (const ushortT*)(ws + OFF_UTH);
    const ushortT* utlB = (const ushortT*)(ws + OFF_UTL);

    // lane's states: n_r = 16w + 4*(l>>4) + r ; d = dq*32 + 16*nt + (l&15)
    float hre[2][4] = {}, him[2][4] = {};
    float a128r[4], a128i[4], bdr[4], bdi[4];
    float cre[2][4], cim[2][4];
    #pragma unroll
    for (int r = 0; r < 4; ++r) {
        const int n = 16 * w + 4 * (l >> 4) + r;
        const float eL = expf(Lre[n]);
        const float xr = dt * (-eL * cosf(Lim[n]));
        const float xi = dt * (-eL * sinf(Lim[n]));
        const float er = expf(128.f * xr);
        float sn, cs; sincosf(128.f * xi, &sn, &cs);
        a128r[r] = er * cs; a128i[r] = er * sn;
        bdr[r] = dt * Bre[n]; bdi[r] = dt * Bim[n];
        #pragma unroll
        for (int nt = 0; nt < 2; ++nt) {
            const int d = dq * 32 + 16 * nt + (l & 15);
            cre[nt][r] = Pre[n * D_ + d]; cim[nt][r] = Pim[n * D_ + d];
        }
    }

    for (int c = 0; c < C_; ++c) {
        const int bc = b * C_ + c;
        // ---- W = C * h (h entering chunk c; c=0 -> zeros), split, stage ---
        #pragma unroll
        for (int nt = 0; nt < 2; ++nt)
            #pragma unroll
            for (int r = 0; r < 4; ++r) {
                const float wr = cre[nt][r] * hre[nt][r] - cim[nt][r] * him[nt][r];
                const float wi = cre[nt][r] * him[nt][r] + cim[nt][r] * hre[nt][r];
                const int dloc = 16 * nt + (l & 15);
                const int nloc = 16 * w + 4 * (l >> 4) + r;
                ushortT hh, ll;
                split2(wr, hh, ll); Wl[0][dloc][nloc] = hh; Wl[1][dloc][nloc] = ll;
                split2(wi, hh, ll); Wl[2][dloc][nloc] = hh; Wl[3][dloc][nloc] = ll;
            }
        __syncthreads();
        {   // coalesced W4 store: thread -> (dloc = t>>3, ng = t&7)
            const int dloc = t >> 3, ng = t & 7;
            #pragma unroll
            for (int p = 0; p < 4; ++p) {
                union { ushortT us[8]; uint4 v; } pk;
                #pragma unroll
                for (int k = 0; k < 8; ++k) pk.us[k] = Wl[p][dloc][8 * ng + k];
                ushortT* W4p = (ushortT*)(ws + OFF_W4 + (size_t)p * W4PLANE);
                *(uint4*)(W4p + (size_t)bc * 16384 + (dq * 32 + dloc) * 64 + 8 * ng) = pk.v;
            }
        }
        __syncthreads();

        // ---- g = Abar @ u_chunk  (M=n 16-tile per wave, N=d 2 tiles) ------
        f32x4 gre[2] = {}, gim[2] = {};
        const ushortT* uthc = uthB + (size_t)bc * 32768;
        const ushortT* utlc = utlB + (size_t)bc * 32768;
        #pragma unroll
        for (int ks = 0; ks < 4; ++ks) {
            const int aoff = (16 * w + (l & 15)) * Q_ + 32 * ks + 8 * (l >> 4);
            const bf16x8 aRh = *(const bf16x8*)(AbReh + aoff);
            const bf16x8 aRl = *(const bf16x8*)(AbRel + aoff);
            const bf16x8 aIh = *(const bf16x8*)(AbImh + aoff);
            const bf16x8 aIl = *(const bf16x8*)(AbIml + aoff);
            #pragma unroll
            for (int nt = 0; nt < 2; ++nt) {
                const int boff = (dq * 32 + 16 * nt + (l & 15)) * Q_ + 32 * ks + 8 * (l >> 4);
                const bf16x8 bh = *(const bf16x8*)(uthc + boff);
                const bf16x8 bl = *(const bf16x8*)(utlc + boff);
                gre[nt] = MFMA(aRh, bh, gre[nt], 0, 0, 0);
                gre[nt] = MFMA(aRh, bl, gre[nt], 0, 0, 0);
                gre[nt] = MFMA(aRl, bh, gre[nt], 0, 0, 0);
                gim[nt] = MFMA(aIh, bh, gim[nt], 0, 0, 0);
                gim[nt] = MFMA(aIh, bl, gim[nt], 0, 0, 0);
                gim[nt] = MFMA(aIl, bh, gim[nt], 0, 0, 0);
            }
        }
        // ---- h = a^128 * h + Bd * g --------------------------------------
        #pragma unroll
        for (int nt = 0; nt < 2; ++nt)
            #pragma unroll
            for (int r = 0; r < 4; ++r) {
                const float gr = gre[nt][r], gi = gim[nt][r];
                const float nr = a128r[r] * hre[nt][r] - a128i[r] * him[nt][r]
                               + bdr[r] * gr - bdi[r] * gi;
                const float ni = a128r[r] * him[nt][r] + a128i[r] * hre[nt][r]
                               + bdr[r] * gi + bdi[r] * gr;
                hre[nt][r] = nr; him[nt][r] = ni;
            }
    }
}

// ---------------------------------------------------------------------------
// G2: per (b,c,dq) block: y_inter = P1@Wre + P2@Wim (MFMA) -> LDS;
// y_intra = 128-tap causal FIR (rolling 16-reg K window); add; store.
// ---------------------------------------------------------------------------
__global__ __launch_bounds__(256)
void g2_kernel(const float* __restrict__ u, const char* __restrict__ ws,
               float* __restrict__ y)
{
    __shared__ float ylds[128][33];

    const int blk = blockIdx.x;
    const int dq = blk & 7, bc = blk >> 3, b = bc >> 2, c = bc & 3;
    const int t = threadIdx.x, l = t & 63, w = t >> 6;

    const ushortT* P1h = (const ushortT*)(ws + OFF_PT);
    const ushortT* P1l = P1h + 8192;
    const ushortT* P2h = P1h + 16384;
    const ushortT* P2l = P1h + 24576;

    // ---- inter GEMM: M=i (2 tiles/wave), K=n(64), N=d (2 tiles) ----------
    f32x4 yac[2][2] = {};
    #pragma unroll
    for (int ks = 0; ks < 2; ++ks) {
        bf16x8 a1h[2], a1l[2], a2h[2], a2l[2];
        #pragma unroll
        for (int mi = 0; mi < 2; ++mi) {
            const int aoff = (32 * w + 16 * mi + (l & 15)) * N_ + 32 * ks + 8 * (l >> 4);
            a1h[mi] = *(const bf16x8*)(P1h + aoff);
            a1l[mi] = *(const bf16x8*)(P1l + aoff);
            a2h[mi] = *(const bf16x8*)(P2h + aoff);
            a2l[mi] = *(const bf16x8*)(P2l + aoff);
        }
        #pragma unroll
        for (int nt = 0; nt < 2; ++nt) {
            const size_t boff = (size_t)bc * 16384
                              + (dq * 32 + 16 * nt + (l & 15)) * 64 + 32 * ks + 8 * (l >> 4);
            const bf16x8 wrh = *(const bf16x8*)((const ushortT*)(ws + OFF_W4 + 0 * W4PLANE) + boff);
            const bf16x8 wrl = *(const bf16x8*)((const ushortT*)(ws + OFF_W4 + 1 * W4PLANE) + boff);
            const bf16x8 wih = *(const bf16x8*)((const ushortT*)(ws + OFF_W4 + 2 * W4PLANE) + boff);
            const bf16x8 wil = *(const bf16x8*)((const ushortT*)(ws + OFF_W4 + 3 * W4PLANE) + boff);
            #pragma unroll
            for (int mi = 0; mi < 2; ++mi) {
                yac[mi][nt] = MFMA(a1h[mi], wrh, yac[mi][nt], 0, 0, 0);
                yac[mi][nt] = MFMA(a1h[mi], wrl, yac[mi][nt], 0, 0, 0);
                yac[mi][nt] = MFMA(a1l[mi], wrh, yac[mi][nt], 0, 0, 0);
                yac[mi][nt] = MFMA(a2h[mi], wih, yac[mi][nt], 0, 0, 0);
                yac[mi][nt] = MFMA(a2h[mi], wil, yac[mi][nt], 0, 0, 0);
                yac[mi][nt] = MFMA(a2l[mi], wih, yac[mi][nt], 0, 0, 0);
            }
        }
    }
    #pragma unroll
    for (int mi = 0; mi < 2; ++mi)
        #pragma unroll
        for (int nt = 0; nt < 2; ++nt)
            #pragma unroll
            for (int r = 0; r < 4; ++r)
                ylds[32 * w + 16 * mi + 4 * (l >> 4) + r][16 * nt + (l & 15)] = yac[mi][nt][r];
    __syncthreads();

    // ---- intra FIR + combine + store -------------------------------------
    const int d = t & 31, ig = t >> 5, i0 = 16 * ig;
    const int dabs = dq * 32 + d;
    const float* Kp = (const float*)(ws + OFF_KPAD) + dabs;        // +row*D_
    const float* uc = u + ((size_t)(b * L_ + c * Q_)) * D_ + dabs; // +j*D_
    float*       yb = y + ((size_t)(b * L_ + c * Q_ + i0)) * D_ + dabs;

    float W16[16];
    W16[0] = 0.f;
    #pragma unroll
    for (int r = 1; r < 16; ++r) W16[r] = Kp[(16 + i0 + r) * D_];
    float acc[16];
    #pragma unroll
    for (int r = 0; r < 16; ++r) acc[r] = 0.f;

    for (int j0 = 0; j0 <= i0; j0 += 16) {
        #pragma unroll
        for (int m = 0; m < 16; ++m) {           // j = j0+m (compile-time idx)
            const int j = j0 + m;
            const float uv = uc[j * D_];
            const float kv = Kp[(16 + i0 - j) * D_];
            acc[0] = fmaf(kv, uv, acc[0]);
            #pragma unroll
            for (int r = 1; r < 16; ++r)
                acc[r] = fmaf(W16[(r - m) & 15], uv, acc[r]);
            W16[(16 - m) & 15] = kv;
        }
    }
    #pragma unroll
    for (int ii = 0; ii < 16; ++ii)
        yb[ii * D_] = acc[ii] + ylds[i0 + ii][d];
}

extern "C" void kernel_launch(void* const* d_in, const int* in_sizes, int n_in,
                              void* d_out, int out_size, void* d_ws, size_t ws_size,
                              hipStream_t stream) {
    const float* u     = (const float*)d_in[0];
    const float* Lre   = (const float*)d_in[1];
    const float* Lim   = (const float*)d_in[2];
    const float* Bre   = (const float*)d_in[3];
    const float* Bim   = (const float*)d_in[4];
    const float* Pre   = (const float*)d_in[5];
    const float* Pim   = (const float*)d_in[6];
    const float* logdt = (const float*)d_in[7];
    float* y = (float*)d_out;
    char* ws = (char*)d_ws;       // needs ~17.1 MB

    kt_kernel<<<209, 256, 0, stream>>>(u, Lre, Lim, Bre, Bim, Pre, Pim, logdt, ws);
    g1s_kernel<<<128, 256, 0, stream>>>(Lre, Lim, Bre, Bim, Pre, Pim, logdt, ws);
    g2_kernel<<<512, 256, 0, stream>>>(u, ws, y);
}

// Round 10
// 78.384 us; speedup vs baseline: 1.1808x; 1.1808x over previous
//
#include <hip/hip_runtime.h>

typedef unsigned short ushortT;
typedef short bf16x8 __attribute__((ext_vector_type(8)));
typedef float f32x4 __attribute__((ext_vector_type(4)));
#define MFMA __builtin_amdgcn_mfma_f32_16x16x32_bf16

#define B_   16
#define L_   512
#define N_   64
#define D_   256
#define Q_   128          // chunk length
#define C_   4            // chunks
#define KROWS 144         // Kpad rows: tau = row-16, rows 0..15 zero

// ---- workspace byte offsets (total ~17.1 MB) ------------------------------
#define OFF_UTH   0u                    // u_T hi  [64 bc][256 d][128 j] bf16
#define OFF_UTL   4194304u              // u_T lo
#define OFF_W4    8388608u              // W planes {reh,rel,imh,iml} [64 bc][256 d][64 n] bf16
#define W4PLANE   2097152u
#define OFF_KPAD  16777216u             // Kpad [144][256] f32
#define OFF_ABT   16924672u             // AbReh,AbRel,AbImh,AbIml each 64x128 bf16
#define OFF_PT    16990208u             // P1h,P1l,P2h,P2l each 128x64 bf16

__device__ __forceinline__ ushortT f2bf(float f) {
    unsigned u = __float_as_uint(f);
    return (ushortT)((u + 0x7FFFu + ((u >> 16) & 1u)) >> 16);   // RNE
}
__device__ __forceinline__ float bf2f(ushortT h) {
    return __uint_as_float(((unsigned)h) << 16);
}
__device__ __forceinline__ void split2(float f, ushortT& hi, ushortT& lo) {
    hi = f2bf(f); lo = f2bf(f - bf2f(hi));
}

// ---------------------------------------------------------------------------
// KT: blocks 0..1023 -> u transpose (bc x 16 j-tiles); 1024..1167 -> Kpad;
//     1168 -> power tables.  All sections latency-fed with plenty of blocks.
// ---------------------------------------------------------------------------
__global__ __launch_bounds__(256)
void kt_kernel(const float* __restrict__ u,
               const float* __restrict__ Lre, const float* __restrict__ Lim,
               const float* __restrict__ Bre, const float* __restrict__ Bim,
               const float* __restrict__ Pre, const float* __restrict__ Pim,
               const float* __restrict__ logdt, char* __restrict__ ws)
{
    const int blk = blockIdx.x, t = threadIdx.x;
    const float dt = expf(logdt[0]);

    if (blk < 1024) {                        // ---- u_T transpose + hi/lo split
        const int bc = blk >> 4, jt = blk & 15, j0 = jt * 8;
        const int b = bc >> 2, c = bc & 3;
        ushortT* uth = (ushortT*)(ws + OFF_UTH) + (size_t)bc * 32768;
        ushortT* utl = (ushortT*)(ws + OFF_UTL) + (size_t)bc * 32768;
        const float* ub = u + ((size_t)(b * L_ + c * Q_ + j0)) * D_ + t;
        float v[8];
        #pragma unroll
        for (int jj = 0; jj < 8; ++jj) v[jj] = ub[jj * D_];   // 8 indep loads
        union { ushortT us[8]; uint4 q; } ph, pl;
        #pragma unroll
        for (int jj = 0; jj < 8; ++jj) split2(v[jj], ph.us[jj], pl.us[jj]);
        *(uint4*)(uth + (size_t)t * Q_ + j0) = ph.q;
        *(uint4*)(utl + (size_t)t * Q_ + j0) = pl.q;

    } else if (blk < 1024 + KROWS) {         // ---- Kpad[row][d] (r3-verified)
        float* Kpad = (float*)(ws + OFF_KPAD);
        __shared__ float U[N_], V[N_];
        const int row = blk - 1024, tau = row - 16, d = t;
        if (tau < 0) { Kpad[row * D_ + d] = 0.f; return; }
        if (d < N_) {
            const float eL = expf(Lre[d]);
            const float wre = -eL * cosf(Lim[d]), wim = -eL * sinf(Lim[d]);
            const float er = expf(tau * dt * wre);
            float sn, cs; sincosf(tau * dt * wim, &sn, &cs);
            const float Ar = er * cs, Ai = er * sn;
            const float bdr = dt * Bre[d], bdi = dt * Bim[d];
            U[d] = bdr * Ar - bdi * Ai;
            V[d] = bdi * Ar + bdr * Ai;
        }
        __syncthreads();
        float acc = 0.f;
        #pragma unroll 8
        for (int n = 0; n < N_; ++n)
            acc = fmaf(Pre[n * D_ + d], U[n], fmaf(-Pim[n * D_ + d], V[n], acc));
        Kpad[row * D_ + d] = acc;

    } else {                                 // ---- Abar & P power tables
        ushortT* AbReh = (ushortT*)(ws + OFF_ABT);
        ushortT* AbRel = AbReh + 8192;
        ushortT* AbImh = AbReh + 16384;
        ushortT* AbIml = AbReh + 24576;
        ushortT* P1h = (ushortT*)(ws + OFF_PT);
        ushortT* P1l = P1h + 8192;
        ushortT* P2h = P1h + 16384;
        ushortT* P2l = P1h + 24576;
        const int n = t & 63, q = t >> 6;
        const float eL = expf(Lre[n]);
        const float xr = dt * (-eL * cosf(Lim[n]));
        const float xi = dt * (-eL * sinf(Lim[n]));
        for (int j = q * 32; j < q * 32 + 32; ++j) {    // Abar[n][j]=a^(127-j)
            const float p = (float)(127 - j);
            const float er = expf(p * xr);
            float sn, cs; sincosf(p * xi, &sn, &cs);
            split2(er * cs, AbReh[n * Q_ + j], AbRel[n * Q_ + j]);
            split2(er * sn, AbImh[n * Q_ + j], AbIml[n * Q_ + j]);
        }
        for (int i = q * 32; i < q * 32 + 32; ++i) {    // P[i][n]: a^(i+1)
            const float p = (float)(i + 1);
            const float er = expf(p * xr);
            float sn, cs; sincosf(p * xi, &sn, &cs);
            split2(er * cs,  P1h[i * N_ + n], P1l[i * N_ + n]);
            split2(-er * sn, P2h[i * N_ + n], P2l[i * N_ + n]);  // -Im
        }
    }
}

// ---------------------------------------------------------------------------
// G1S: per (b, dq16) block: serial over c: W=C*h store; g = Abar@u (MFMA,
// split bf16); h = a^128 h + Bd*g.  4 waves = 4 n-tiles, d-tile = 16.
// ---------------------------------------------------------------------------
__global__ __launch_bounds__(256)
void g1s_kernel(const float* __restrict__ Lre, const float* __restrict__ Lim,
                const float* __restrict__ Bre, const float* __restrict__ Bim,
                const float* __restrict__ Pre, const float* __restrict__ Pim,
                const float* __restrict__ logdt, char* __restrict__ ws)
{
    __shared__ ushortT Wl[4][16][65];        // plane, d_loc, n (pad 65)

    const int blk = blockIdx.x, b = blk >> 4, dq = blk & 15;
    const int t = threadIdx.x, l = t & 63, w = t >> 6;     // w = n-tile
    const float dt = expf(logdt[0]);

    const ushortT* AbReh = (const ushortT*)(ws + OFF_ABT);
    const ushortT* AbRel = AbReh + 8192;
    const ushortT* AbImh = AbReh + 16384;
    const ushortT* AbIml = AbReh + 24576;
    const ushortT* uthB = (const ushortT*)(ws + OFF_UTH);
    const ushortT* utlB = (const ushortT*)(ws + OFF_UTL);

    // lane's states: n_r = 16w + 4*(l>>4) + r ; d = dq*16 + (l&15)
    const int dloc = l & 15;
    const int dabs = dq * 16 + dloc;
    float hre[4] = {}, him[4] = {};
    float a128r[4], a128i[4], bdr[4], bdi[4], cre[4], cim[4];
    #pragma unroll
    for (int r = 0; r < 4; ++r) {
        const int n = 16 * w + 4 * (l >> 4) + r;
        const float eL = expf(Lre[n]);
        const float xr = dt * (-eL * cosf(Lim[n]));
        const float xi = dt * (-eL * sinf(Lim[n]));
        const float er = expf(128.f * xr);
        float sn, cs; sincosf(128.f * xi, &sn, &cs);
        a128r[r] = er * cs; a128i[r] = er * sn;
        bdr[r] = dt * Bre[n]; bdi[r] = dt * Bim[n];
        cre[r] = Pre[n * D_ + dabs]; cim[r] = Pim[n * D_ + dabs];
    }

    for (int c = 0; c < C_; ++c) {
        const int bc = b * C_ + c;
        // ---- W = C * h (h entering chunk c), split, stage in LDS ---------
        #pragma unroll
        for (int r = 0; r < 4; ++r) {
            const float wr = cre[r] * hre[r] - cim[r] * him[r];
            const float wi = cre[r] * him[r] + cim[r] * hre[r];
            const int nloc = 16 * w + 4 * (l >> 4) + r;
            ushortT hh, ll;
            split2(wr, hh, ll); Wl[0][dloc][nloc] = hh; Wl[1][dloc][nloc] = ll;
            split2(wi, hh, ll); Wl[2][dloc][nloc] = hh; Wl[3][dloc][nloc] = ll;
        }
        __syncthreads();
        {   // coalesced W4 store: 512 uint4 total, 2 per thread
            #pragma unroll
            for (int it = 0; it < 2; ++it) {
                const int q = t + 256 * it;
                const int p = q >> 7, rem = q & 127;
                const int dl = rem >> 3, ng = rem & 7;
                union { ushortT us[8]; uint4 v; } pk;
                #pragma unroll
                for (int kx = 0; kx < 8; ++kx) pk.us[kx] = Wl[p][dl][8 * ng + kx];
                ushortT* W4p = (ushortT*)(ws + OFF_W4 + (size_t)p * W4PLANE);
                *(uint4*)(W4p + (size_t)bc * 16384 + (dq * 16 + dl) * 64 + 8 * ng) = pk.v;
            }
        }
        __syncthreads();

        // ---- g = Abar @ u_chunk  (M = n-tile per wave, N = 16 d) ---------
        f32x4 gre = {}, gim = {};
        const ushortT* uthc = uthB + (size_t)bc * 32768;
        const ushortT* utlc = utlB + (size_t)bc * 32768;
        #pragma unroll
        for (int ks = 0; ks < 4; ++ks) {
            const int aoff = (16 * w + (l & 15)) * Q_ + 32 * ks + 8 * (l >> 4);
            const bf16x8 aRh = *(const bf16x8*)(AbReh + aoff);
            const bf16x8 aRl = *(const bf16x8*)(AbRel + aoff);
            const bf16x8 aIh = *(const bf16x8*)(AbImh + aoff);
            const bf16x8 aIl = *(const bf16x8*)(AbIml + aoff);
            const int boff = dabs * Q_ + 32 * ks + 8 * (l >> 4);
            const bf16x8 bh = *(const bf16x8*)(uthc + boff);
            const bf16x8 bl = *(const bf16x8*)(utlc + boff);
            gre = MFMA(aRh, bh, gre, 0, 0, 0);
            gre = MFMA(aRh, bl, gre, 0, 0, 0);
            gre = MFMA(aRl, bh, gre, 0, 0, 0);
            gim = MFMA(aIh, bh, gim, 0, 0, 0);
            gim = MFMA(aIh, bl, gim, 0, 0, 0);
            gim = MFMA(aIl, bh, gim, 0, 0, 0);
        }
        // ---- h = a^128 * h + Bd * g --------------------------------------
        #pragma unroll
        for (int r = 0; r < 4; ++r) {
            const float gr = gre[r], gi = gim[r];
            const float nr = a128r[r] * hre[r] - a128i[r] * him[r]
                           + bdr[r] * gr - bdi[r] * gi;
            const float ni = a128r[r] * him[r] + a128i[r] * hre[r]
                           + bdr[r] * gi + bdi[r] * gr;
            hre[r] = nr; him[r] = ni;
        }
    }
}

// ---------------------------------------------------------------------------
// G2: per (b,c,dq32) block: y_inter = P1@Wre + P2@Wim (MFMA) -> LDS;
// u-chunk + Kpad column staged in LDS; 128-tap causal FIR from LDS; add; store.
// ---------------------------------------------------------------------------
__global__ __launch_bounds__(256)
void g2_kernel(const float* __restrict__ u, const char* __restrict__ ws,
               float* __restrict__ y)
{
    __shared__ float ylds[128][33];          // 16.9 KB
    __shared__ float uS[Q_ * 32];            // 16   KB  [j][d32]
    __shared__ float kS[KROWS * 32];         // 18.4 KB  [row][d32]

    const int blk = blockIdx.x;
    const int dq = blk & 7, bc = blk >> 3, b = bc >> 2, c = bc & 3;
    const int t = threadIdx.x, l = t & 63, w = t >> 6;

    // ---- stage u chunk + Kpad column (issue before GEMM; barrier below) --
    {
        const float* ug = u + ((size_t)(b * L_ + c * Q_)) * D_ + dq * 32;
        const float* Kg = (const float*)(ws + OFF_KPAD) + dq * 32;
        const int row0 = t >> 5, dl = t & 31;         // 8 rows per pass
        #pragma unroll
        for (int it = 0; it < Q_ / 8; ++it)
            uS[(row0 + 8 * it) * 32 + dl] = ug[(size_t)(row0 + 8 * it) * D_ + dl];
        #pragma unroll
        for (int it = 0; it < KROWS / 8; ++it)
            kS[(row0 + 8 * it) * 32 + dl] = Kg[(size_t)(row0 + 8 * it) * D_ + dl];
    }

    const ushortT* P1h = (const ushortT*)(ws + OFF_PT);
    const ushortT* P1l = P1h + 8192;
    const ushortT* P2h = P1h + 16384;
    const ushortT* P2l = P1h + 24576;

    // ---- inter GEMM: M=i (2 tiles/wave), K=n(64), N=d (2 tiles) ----------
    f32x4 yac[2][2] = {};
    #pragma unroll
    for (int ks = 0; ks < 2; ++ks) {
        bf16x8 a1h[2], a1l[2], a2h[2], a2l[2];
        #pragma unroll
        for (int mi = 0; mi < 2; ++mi) {
            const int aoff = (32 * w + 16 * mi + (l & 15)) * N_ + 32 * ks + 8 * (l >> 4);
            a1h[mi] = *(const bf16x8*)(P1h + aoff);
            a1l[mi] = *(const bf16x8*)(P1l + aoff);
            a2h[mi] = *(const bf16x8*)(P2h + aoff);
            a2l[mi] = *(const bf16x8*)(P2l + aoff);
        }
        #pragma unroll
        for (int nt = 0; nt < 2; ++nt) {
            const size_t boff = (size_t)bc * 16384
                              + (dq * 32 + 16 * nt + (l & 15)) * 64 + 32 * ks + 8 * (l >> 4);
            const bf16x8 wrh = *(const bf16x8*)((const ushortT*)(ws + OFF_W4 + 0 * W4PLANE) + boff);
            const bf16x8 wrl = *(const bf16x8*)((const ushortT*)(ws + OFF_W4 + 1 * W4PLANE) + boff);
            const bf16x8 wih = *(const bf16x8*)((const ushortT*)(ws + OFF_W4 + 2 * W4PLANE) + boff);
            const bf16x8 wil = *(const bf16x8*)((const ushortT*)(ws + OFF_W4 + 3 * W4PLANE) + boff);
            #pragma unroll
            for (int mi = 0; mi < 2; ++mi) {
                yac[mi][nt] = MFMA(a1h[mi], wrh, yac[mi][nt], 0, 0, 0);
                yac[mi][nt] = MFMA(a1h[mi], wrl, yac[mi][nt], 0, 0, 0);
                yac[mi][nt] = MFMA(a1l[mi], wrh, yac[mi][nt], 0, 0, 0);
                yac[mi][nt] = MFMA(a2h[mi], wih, yac[mi][nt], 0, 0, 0);
                yac[mi][nt] = MFMA(a2h[mi], wil, yac[mi][nt], 0, 0, 0);
                yac[mi][nt] = MFMA(a2l[mi], wih, yac[mi][nt], 0, 0, 0);
            }
        }
    }
    #pragma unroll
    for (int mi = 0; mi < 2; ++mi)
        #pragma unroll
        for (int nt = 0; nt < 2; ++nt)
            #pragma unroll
            for (int r = 0; r < 4; ++r)
                ylds[32 * w + 16 * mi + 4 * (l >> 4) + r][16 * nt + (l & 15)] = yac[mi][nt][r];
    __syncthreads();     // staging + ylds both visible

    // ---- intra FIR (all LDS) + combine + store ---------------------------
    const int d = t & 31, ig = t >> 5, i0 = 16 * ig;
    const int dabs = dq * 32 + d;
    float*       yb = y + ((size_t)(b * L_ + c * Q_ + i0)) * D_ + dabs;

    float W16[16];
    W16[0] = 0.f;
    #pragma unroll
    for (int r = 1; r < 16; ++r) W16[r] = kS[(16 + i0 + r) * 32 + d];
    float acc[16];
    #pragma unroll
    for (int r = 0; r < 16; ++r) acc[r] = 0.f;

    for (int j0 = 0; j0 <= i0; j0 += 16) {
        #pragma unroll
        for (int m = 0; m < 16; ++m) {           // j = j0+m
            const int j = j0 + m;
            const float uv = uS[j * 32 + d];
            const float kv = kS[(16 + i0 - j) * 32 + d];
            acc[0] = fmaf(kv, uv, acc[0]);
            #pragma unroll
            for (int r = 1; r < 16; ++r)
                acc[r] = fmaf(W16[(r - m) & 15], uv, acc[r]);
            W16[(16 - m) & 15] = kv;
        }
    }
    #pragma unroll
    for (int ii = 0; ii < 16; ++ii)
        yb[ii * D_] = acc[ii] + ylds[i0 + ii][d];
}

extern "C" void kernel_launch(void* const* d_in, const int* in_sizes, int n_in,
                              void* d_out, int out_size, void* d_ws, size_t ws_size,
                              hipStream_t stream) {
    const float* u     = (const float*)d_in[0];
    const float* Lre   = (const float*)d_in[1];
    const float* Lim   = (const float*)d_in[2];
    const float* Bre   = (const float*)d_in[3];
    const float* Bim   = (const float*)d_in[4];
    const float* Pre   = (const float*)d_in[5];
    const float* Pim   = (const float*)d_in[6];
    const float* logdt = (const float*)d_in[7];
    float* y = (float*)d_out;
    char* ws = (char*)d_ws;       // needs ~17.1 MB

    kt_kernel<<<1024 + KROWS + 1, 256, 0, stream>>>(u, Lre, Lim, Bre, Bim,
                                                    Pre, Pim, logdt, ws);
    g1s_kernel<<<256, 256, 0, stream>>>(Lre, Lim, Bre, Bim, Pre, Pim, logdt, ws);
    g2_kernel<<<512, 256, 0, stream>>>(u, ws, y);
}

// Round 11
// 60.146 us; speedup vs baseline: 1.5388x; 1.3032x over previous
//
#include <hip/hip_runtime.h>

typedef unsigned short ushortT;
typedef short bf16x8 __attribute__((ext_vector_type(8)));
typedef float f32x4 __attribute__((ext_vector_type(4)));
#define MFMA __builtin_amdgcn_mfma_f32_16x16x32_bf16

#define B_ 16
#define L_ 512
#define N_ 64
#define D_ 256
#define Q_ 128
#define KROWS 144

// ---- workspace byte offsets (total ~6.6 MB) -------------------------------
#define OFF_GRE  0u          // g_re [48 bc3][64 n][256 d] f32  (bc3=b*3+c, c<3)
#define OFF_GIM  3145728u    // g_im
#define OFF_KPAD 6291456u    // Kpad [144][256] f32 (rows 0..15 zero)
#define OFF_ABT  6438912u    // AbReh/AbRel/AbImh/AbIml  64x128 bf16 each
#define OFF_PT   6504448u    // P1h/P1l/P2h/P2l          128x64 bf16 each

__device__ __forceinline__ ushortT f2bf(float f) {
    unsigned u = __float_as_uint(f);
    return (ushortT)((u + 0x7FFFu + ((u >> 16) & 1u)) >> 16);   // RNE
}
__device__ __forceinline__ float bf2f(ushortT h) {
    return __uint_as_float(((unsigned)h) << 16);
}
__device__ __forceinline__ void split2(float f, ushortT& hi, ushortT& lo) {
    hi = f2bf(f); lo = f2bf(f - bf2f(hi));
}

// ---------------------------------------------------------------------------
// prep: blocks 0..143 -> Kpad rows; block 144 -> Ab & P power tables.
// ---------------------------------------------------------------------------
__global__ __launch_bounds__(256)
void prep_kernel(const float* __restrict__ Lre, const float* __restrict__ Lim,
                 const float* __restrict__ Bre, const float* __restrict__ Bim,
                 const float* __restrict__ Pre, const float* __restrict__ Pim,
                 const float* __restrict__ logdt, char* __restrict__ ws)
{
    const int blk = blockIdx.x, t = threadIdx.x;
    const float dt = expf(logdt[0]);

    if (blk < KROWS) {                       // ---- Kpad[row][d] (r3-verified)
        float* Kpad = (float*)(ws + OFF_KPAD);
        __shared__ float U[N_], V[N_];
        const int row = blk, tau = row - 16, d = t;
        if (tau < 0) { Kpad[row * D_ + d] = 0.f; return; }
        if (d < N_) {
            const float eL = expf(Lre[d]);
            const float wre = -eL * cosf(Lim[d]), wim = -eL * sinf(Lim[d]);
            const float er = expf(tau * dt * wre);
            float sn, cs; sincosf(tau * dt * wim, &sn, &cs);
            const float Ar = er * cs, Ai = er * sn;
            const float bdr = dt * Bre[d], bdi = dt * Bim[d];
            U[d] = bdr * Ar - bdi * Ai;
            V[d] = bdi * Ar + bdr * Ai;
        }
        __syncthreads();
        float acc = 0.f;
        #pragma unroll 8
        for (int n = 0; n < N_; ++n)
            acc = fmaf(Pre[n * D_ + d], U[n], fmaf(-Pim[n * D_ + d], V[n], acc));
        Kpad[row * D_ + d] = acc;

    } else {                                 // ---- Abar & P power tables
        ushortT* AbReh = (ushortT*)(ws + OFF_ABT);
        ushortT* AbRel = AbReh + 8192;
        ushortT* AbImh = AbReh + 16384;
        ushortT* AbIml = AbReh + 24576;
        ushortT* P1h = (ushortT*)(ws + OFF_PT);
        ushortT* P1l = P1h + 8192;
        ushortT* P2h = P1h + 16384;
        ushortT* P2l = P1h + 24576;
        const int n = t & 63, q = t >> 6;
        const float eL = expf(Lre[n]);
        const float xr = dt * (-eL * cosf(Lim[n]));
        const float xi = dt * (-eL * sinf(Lim[n]));
        for (int j = q * 32; j < q * 32 + 32; ++j) {    // Abar[n][j]=a^(127-j)
            const float p = (float)(127 - j);
            const float er = expf(p * xr);
            float sn, cs; sincosf(p * xi, &sn, &cs);
            split2(er * cs, AbReh[n * Q_ + j], AbRel[n * Q_ + j]);
            split2(er * sn, AbImh[n * Q_ + j], AbIml[n * Q_ + j]);
        }
        for (int i = q * 32; i < q * 32 + 32; ++i) {    // P[i][n] from a^(i+1)
            const float p = (float)(i + 1);
            const float er = expf(p * xr);
            float sn, cs; sincosf(p * xi, &sn, &cs);
            split2(er * cs,  P1h[i * N_ + n], P1l[i * N_ + n]);
            split2(-er * sn, P2h[i * N_ + n], P2l[i * N_ + n]);  // -Im
        }
    }
}

// ---------------------------------------------------------------------------
// gstage: grid 768 = (bc3 = b*3+c, c<3) x 16 d-tiles. Fully parallel.
// Stage u chunk-slice [128 j][16 d] -> LDS transposed+split; g = Ab@u (MFMA);
// store g[bc3][n][d] f32 coalesced. No serial chain, no u_T workspace.
// ---------------------------------------------------------------------------
__global__ __launch_bounds__(256, 2)
void gstage_kernel(const float* __restrict__ u, char* __restrict__ ws)
{
    __shared__ ushortT ldsH[16][136];        // [dl][j], stride 136 (16B-aligned)
    __shared__ ushortT ldsL[16][136];

    const int blk = blockIdx.x;              // 0..767
    const int bc3 = blk >> 4, dq = blk & 15;
    const int b = bc3 / 3, c = bc3 % 3;
    const int t = threadIdx.x, l = t & 63, w = t >> 6;   // w = n-tile

    {   // stage + split + transpose
        const int dl = t & 15, j0 = t >> 4;
        const float* ug = u + ((size_t)(b * L_ + c * Q_) * D_) + dq * 16 + dl;
        #pragma unroll
        for (int p = 0; p < 8; ++p) {
            const int j = j0 + 16 * p;
            ushortT hh, ll;
            split2(ug[(size_t)j * D_], hh, ll);
            ldsH[dl][j] = hh; ldsL[dl][j] = ll;
        }
    }
    __syncthreads();

    const ushortT* AbReh = (const ushortT*)(ws + OFF_ABT);
    const ushortT* AbRel = AbReh + 8192;
    const ushortT* AbImh = AbReh + 16384;
    const ushortT* AbIml = AbReh + 24576;

    f32x4 gre = {}, gim = {};
    #pragma unroll
    for (int ks = 0; ks < 4; ++ks) {
        const int aoff = (16 * w + (l & 15)) * Q_ + 32 * ks + 8 * (l >> 4);
        const bf16x8 aRh = *(const bf16x8*)(AbReh + aoff);
        const bf16x8 aRl = *(const bf16x8*)(AbRel + aoff);
        const bf16x8 aIh = *(const bf16x8*)(AbImh + aoff);
        const bf16x8 aIl = *(const bf16x8*)(AbIml + aoff);
        const int boff = (l & 15) * 136 + 32 * ks + 8 * (l >> 4);
        const bf16x8 bh = *(const bf16x8*)(&ldsH[0][0] + boff);
        const bf16x8 bl = *(const bf16x8*)(&ldsL[0][0] + boff);
        gre = MFMA(aRh, bh, gre, 0, 0, 0);
        gre = MFMA(aRh, bl, gre, 0, 0, 0);
        gre = MFMA(aRl, bh, gre, 0, 0, 0);
        gim = MFMA(aIh, bh, gim, 0, 0, 0);
        gim = MFMA(aIh, bl, gim, 0, 0, 0);
        gim = MFMA(aIl, bh, gim, 0, 0, 0);
    }

    float* gre_p = (float*)(ws + OFF_GRE);
    float* gim_p = (float*)(ws + OFF_GIM);
    #pragma unroll
    for (int r = 0; r < 4; ++r) {            // D: col=l&15, row=4*(l>>4)+r
        const int n = 16 * w + 4 * (l >> 4) + r;
        gre_p[((size_t)bc3 * N_ + n) * D_ + dq * 16 + (l & 15)] = gre[r];
        gim_p[((size_t)bc3 * N_ + n) * D_ + dq * 16 + (l & 15)] = gim[r];
    }
}

// ---------------------------------------------------------------------------
// out: grid 512 = (b,c) x 8 d32-tiles.  h-combine (<=3 cFMA) -> W -> LDS ->
// P@W GEMM -> ylds;  FIR from LDS (uS bf16, kS incl. 16 zero rows); add; store.
// ---------------------------------------------------------------------------
__global__ __launch_bounds__(256, 2)
void out_kernel(const float* __restrict__ u,
                const float* __restrict__ Lre, const float* __restrict__ Lim,
                const float* __restrict__ Bre, const float* __restrict__ Bim,
                const float* __restrict__ Pre, const float* __restrict__ Pim,
                const float* __restrict__ logdt, const char* __restrict__ ws,
                float* __restrict__ y)
{
    __shared__ float   ylds[128][33];        // 16.9 KB
    __shared__ ushortT Wl[4][32][72];        // 18.4 KB (stride 72: 16B-aligned)
    __shared__ ushortT uS[Q_][32];           //  8   KB (bf16)
    __shared__ float   kS[KROWS][32];        // 18.4 KB (rows 0..15 zero)

    const int blk = blockIdx.x;              // 0..511
    const int dq = blk & 7, bc = blk >> 3, b = bc >> 2, c = bc & 3;
    const int t = threadIdx.x, l = t & 63, w = t >> 6;
    const float dt = expf(logdt[0]);

    // ---- stage uS (bf16) + kS (coalesced 128B rows) ----------------------
    {
        const float* ug = u + ((size_t)(b * L_ + c * Q_) * D_) + dq * 32;
        const float* Kg = (const float*)(ws + OFF_KPAD) + dq * 32;
        #pragma unroll
        for (int it = 0; it < 16; ++it) {
            const int idx = t + 256 * it, r = idx >> 5, dl = idx & 31;
            uS[r][dl] = f2bf(ug[(size_t)r * D_ + dl]);
        }
        #pragma unroll
        for (int it = 0; it < 18; ++it) {
            const int idx = t + 256 * it, r = idx >> 5, dl = idx & 31;
            kS[r][dl] = Kg[(size_t)r * D_ + dl];
        }
    }

    // ---- h-combine + W = C*h (skip for c==0) -----------------------------
    if (c > 0) {
        const float* gre_p = (const float*)(ws + OFF_GRE);
        const float* gim_p = (const float*)(ws + OFF_GIM);
        #pragma unroll
        for (int r = 0; r < 4; ++r) {
            const int n = 16 * w + 4 * (l >> 4) + r;
            const float eL = expf(Lre[n]);
            const float xr = dt * (-eL * cosf(Lim[n]));
            const float xi = dt * (-eL * sinf(Lim[n]));
            const float er = expf(128.f * xr);
            float sn, cs; sincosf(128.f * xi, &sn, &cs);
            const float qr = er * cs, qi = er * sn;            // a^128
            const float bdr = dt * Bre[n], bdi = dt * Bim[n];
            #pragma unroll
            for (int nt = 0; nt < 2; ++nt) {
                const int d = dq * 32 + 16 * nt + (l & 15);
                float hr = 0.f, hi = 0.f, pr = 1.f, pi = 0.f;
                for (int cp = c - 1; cp >= 0; --cp) {          // p = q^(c-1-cp)
                    const size_t go = ((size_t)(b * 3 + cp) * N_ + n) * D_ + d;
                    const float gr = gre_p[go], gi = gim_p[go];
                    const float tr = bdr * gr - bdi * gi;
                    const float ti = bdr * gi + bdi * gr;
                    hr += tr * pr - ti * pi;
                    hi += tr * pi + ti * pr;
                    const float npr = pr * qr - pi * qi;
                    const float npi = pr * qi + pi * qr;
                    pr = npr; pi = npi;
                }
                const float cr = Pre[n * D_ + d], ci = Pim[n * D_ + d];
                const float wr = cr * hr - ci * hi;
                const float wi = cr * hi + ci * hr;
                const int dl = 16 * nt + (l & 15);
                ushortT hh, ll;
                split2(wr, hh, ll); Wl[0][dl][n] = hh; Wl[1][dl][n] = ll;
                split2(wi, hh, ll); Wl[2][dl][n] = hh; Wl[3][dl][n] = ll;
            }
        }
    }
    __syncthreads();

    // ---- inter GEMM (or zeros for c==0) ----------------------------------
    if (c > 0) {
        const ushortT* P1h = (const ushortT*)(ws + OFF_PT);
        const ushortT* P1l = P1h + 8192;
        const ushortT* P2h = P1h + 16384;
        const ushortT* P2l = P1h + 24576;
        f32x4 yac[2][2] = {};
        #pragma unroll
        for (int ks = 0; ks < 2; ++ks) {
            bf16x8 a1h[2], a1l[2], a2h[2], a2l[2];
            #pragma unroll
            for (int mi = 0; mi < 2; ++mi) {
                const int aoff = (32 * w + 16 * mi + (l & 15)) * N_ + 32 * ks + 8 * (l >> 4);
                a1h[mi] = *(const bf16x8*)(P1h + aoff);
                a1l[mi] = *(const bf16x8*)(P1l + aoff);
                a2h[mi] = *(const bf16x8*)(P2h + aoff);
                a2l[mi] = *(const bf16x8*)(P2l + aoff);
            }
            #pragma unroll
            for (int nt = 0; nt < 2; ++nt) {
                const int boff = (16 * nt + (l & 15)) * 72 + 32 * ks + 8 * (l >> 4);
                const bf16x8 wrh = *(const bf16x8*)(&Wl[0][0][0] + boff);
                const bf16x8 wrl = *(const bf16x8*)(&Wl[1][0][0] + boff);
                const bf16x8 wih = *(const bf16x8*)(&Wl[2][0][0] + boff);
                const bf16x8 wil = *(const bf16x8*)(&Wl[3][0][0] + boff);
                #pragma unroll
                for (int mi = 0; mi < 2; ++mi) {
                    yac[mi][nt] = MFMA(a1h[mi], wrh, yac[mi][nt], 0, 0, 0);
                    yac[mi][nt] = MFMA(a1h[mi], wrl, yac[mi][nt], 0, 0, 0);
                    yac[mi][nt] = MFMA(a1l[mi], wrh, yac[mi][nt], 0, 0, 0);
                    yac[mi][nt] = MFMA(a2h[mi], wih, yac[mi][nt], 0, 0, 0);
                    yac[mi][nt] = MFMA(a2h[mi], wil, yac[mi][nt], 0, 0, 0);
                    yac[mi][nt] = MFMA(a2l[mi], wih, yac[mi][nt], 0, 0, 0);
                }
            }
        }
        #pragma unroll
        for (int mi = 0; mi < 2; ++mi)
            #pragma unroll
            for (int nt = 0; nt < 2; ++nt)
                #pragma unroll
                for (int r = 0; r < 4; ++r)
                    ylds[32 * w + 16 * mi + 4 * (l >> 4) + r][16 * nt + (l & 15)] = yac[mi][nt][r];
    } else {
        #pragma unroll
        for (int it = 0; it < 16; ++it) {
            const int idx = t + 256 * it;
            ylds[idx >> 5][idx & 31] = 0.f;
        }
    }
    __syncthreads();

    // ---- intra FIR (LDS) + add + store -----------------------------------
    const int d = t & 31, ig = t >> 5, i0 = 16 * ig;
    float* yb = y + ((size_t)(b * L_ + c * Q_ + i0)) * D_ + dq * 32 + d;

    float W16[16];
    W16[0] = 0.f;
    #pragma unroll
    for (int r = 1; r < 16; ++r) W16[r] = kS[16 + i0 + r][d];
    float acc[16];
    #pragma unroll
    for (int r = 0; r < 16; ++r) acc[r] = 0.f;

    for (int j0 = 0; j0 <= i0; j0 += 16) {
        #pragma unroll
        for (int m = 0; m < 16; ++m) {           // j = j0+m
            const int j = j0 + m;
            const float uv = bf2f(uS[j][d]);
            const float kv = kS[16 + i0 - j][d];     // rows 0..15 are zeros
            acc[0] = fmaf(kv, uv, acc[0]);
            #pragma unroll
            for (int r = 1; r < 16; ++r)
                acc[r] = fmaf(W16[(r - m) & 15], uv, acc[r]);
            W16[(16 - m) & 15] = kv;
        }
    }
    #pragma unroll
    for (int ii = 0; ii < 16; ++ii)
        yb[ii * D_] = acc[ii] + ylds[i0 + ii][d];
}

extern "C" void kernel_launch(void* const* d_in, const int* in_sizes, int n_in,
                              void* d_out, int out_size, void* d_ws, size_t ws_size,
                              hipStream_t stream) {
    const float* u     = (const float*)d_in[0];
    const float* Lre   = (const float*)d_in[1];
    const float* Lim   = (const float*)d_in[2];
    const float* Bre   = (const float*)d_in[3];
    const float* Bim   = (const float*)d_in[4];
    const float* Pre   = (const float*)d_in[5];
    const float* Pim   = (const float*)d_in[6];
    const float* logdt = (const float*)d_in[7];
    float* y = (float*)d_out;
    char* ws = (char*)d_ws;       // ~6.6 MB used

    prep_kernel<<<KROWS + 1, 256, 0, stream>>>(Lre, Lim, Bre, Bim, Pre, Pim, logdt, ws);
    gstage_kernel<<<768, 256, 0, stream>>>(u, ws);
    out_kernel<<<512, 256, 0, stream>>>(u, Lre, Lim, Bre, Bim, Pre, Pim, logdt, ws, y);
}